// Round 3
// baseline (4167.702 us; speedup 1.0000x reference)
//
#include <hip/hip_runtime.h>
#include <hip/hip_bf16.h>
#include <cstddef>

#define NB 2048
#define TENC 168
#define TPRED 24

// ---------------------------------------------------------------------------
// Phase 1: recurrent dilated-conv decoder. One wave (64 lanes) per batch
// element; 8 elements per 512-thread block; 256 blocks total.
//
// Round 3: t/l loop bounds are RUNTIME kernel arguments so the compiler
// cannot fully unroll them (rounds 1-2 show identical VGPR/SGPR/FETCH/WRITE
// -> both compiled to a fully-unrolled ~1MB body -> L1I streaming at IPC
// 0.03). No fences/barriers in the loop: all LDS state (sx/gt/ring) is
// wave-private; DS ops of a wave complete in program order, and the
// compiler orders may-aliasing LDS reads after writes with counted lgkmcnt.
// Weights packed as float4 over input pairs: 96 LDS reads/layer-step.
// ---------------------------------------------------------------------------
__global__ __launch_bounds__(512, 1) void dec_phase1(
    const float* __restrict__ feat,    // [2048][24][15]
    const float* __restrict__ dinit,   // [2048][1]
    const float* __restrict__ enc,     // [6][2048][168][64]
    const float* __restrict__ W1,      // [16][64]
    const float* __restrict__ b1,      // [64]
    const float* __restrict__ W2,      // [64][128]
    const float* __restrict__ b2,      // [128]
    const float* __restrict__ W3,      // [64][128]
    const float* __restrict__ W4,      // [64][128]
    const float* __restrict__ b4,      // [128]
    float* __restrict__ skbuf,         // [2048*24][6*64]
    int t_steps, int n_layers)         // runtime: 24, 6 (blocks full unroll)
{
  // W23q[i2*64+p] = { W23[2*i2][p], W23[2*i2][p+64],
  //                   W23[2*i2+1][p], W23[2*i2+1][p+64] }
  // where W23 rows 0..63 = W2 (state half), rows 64..127 = W3 (x half).
  __shared__ float4 W23q[64 * 64];     // 64 KB
  __shared__ float4 W4q[32 * 64];      // 32 KB
  __shared__ float  W1s[16 * 64];      // 4 KB
  __shared__ float  b2s[128], b4s[128], b1s[64];
  __shared__ float  ring[8][23 * 64];  // 46 KB (per-element dilation rings)
  __shared__ float  sx[8][128];        // [state | x] per element
  __shared__ float  gt[8][64];         // gated per element

  const int tid = threadIdx.x;

  for (int k = tid; k < 64 * 64; k += 512) {
    const int i2 = k >> 6, p = k & 63;
    const float* r0 = (i2 < 32) ? (W2 + (2 * i2) * 128)
                                : (W3 + (2 * i2 - 64) * 128);
    W23q[k] = make_float4(r0[p], r0[p + 64], r0[128 + p], r0[128 + p + 64]);
  }
  for (int k = tid; k < 32 * 64; k += 512) {
    const int i2 = k >> 6, p = k & 63;
    const float* r0 = W4 + (2 * i2) * 128;
    W4q[k] = make_float4(r0[p], r0[p + 64], r0[128 + p], r0[128 + p + 64]);
  }
  for (int k = tid; k < 16 * 64; k += 512) W1s[k] = W1[k];
  if (tid < 128) { b2s[tid] = b2[tid]; b4s[tid] = b4[tid]; }
  else if (tid < 192) b1s[tid - 128] = b1[tid - 128];
  __syncthreads();   // the only block-wide barrier

  const int wid  = tid >> 6;
  const int lane = tid & 63;
  const int e    = blockIdx.x * 8 + wid;
  const float ini = dinit[e];

  for (int t = 0; t < t_steps; ++t) {
    // ---- input embedding: x = tanh([init, feat_t] @ W1 + b1) ----
    float u = b1s[lane] + ini * W1s[lane];
    const float* fp = feat + ((size_t)e * TPRED + t) * 15;
    #pragma unroll
    for (int i = 0; i < 15; ++i) u += fp[i] * W1s[(i + 1) * 64 + lane];
    float x = tanhf(u);
    sx[wid][64 + lane] = x;

    for (int l = 0; l < n_layers; ++l) {
      const int d    = 1 << l;
      const int roff = d - 1;           // ring base: l=0..4 -> 0,1,3,7,15
      const int msk  = (d - 1) & 7;     // ring slot mask (sizes 1,2,4,8,8)

      // ---- state ----
      float st;
      if (t < d) {
        st = enc[(((size_t)l * NB + e) * TENC + (TENC + t - d)) * 64 + lane];
      } else {
        st = ring[wid][(roff + (t & msk)) * 64 + lane];
      }
      sx[wid][lane] = st;

      // ---- dc = [state|x] @ [W2;W3] + b2 ; lane owns cols (lane, lane+64) --
      float a = b2s[lane], b = b2s[64 + lane];
      #pragma unroll
      for (int i = 0; i < 128; i += 4) {
        const float4 s4 = *(const float4*)&sx[wid][i];
        const float4 w0 = W23q[(i >> 1) * 64 + lane];
        const float4 w1 = W23q[((i >> 1) + 1) * 64 + lane];
        a += s4.x * w0.x; b += s4.x * w0.y;
        a += s4.y * w0.z; b += s4.y * w0.w;
        a += s4.z * w1.x; b += s4.z * w1.y;
        a += s4.w * w1.z; b += s4.w * w1.w;
      }
      const float gg = tanhf(a) * (1.0f / (1.0f + __expf(-b)));
      gt[wid][lane] = gg;

      // ---- out = gated @ W4 + b4 ; skip = out[:64], res = out[64:] ----
      float sk = b4s[lane], rs = b4s[64 + lane];
      #pragma unroll
      for (int i = 0; i < 64; i += 4) {
        const float4 g4 = *(const float4*)&gt[wid][i];
        const float4 w0 = W4q[(i >> 1) * 64 + lane];
        const float4 w1 = W4q[((i >> 1) + 1) * 64 + lane];
        sk += g4.x * w0.x; rs += g4.x * w0.y;
        sk += g4.y * w0.z; rs += g4.y * w0.w;
        sk += g4.z * w1.x; rs += g4.z * w1.y;
        sk += g4.w * w1.z; rs += g4.w * w1.w;
      }
      const float xn = sx[wid][64 + lane] + rs;
      skbuf[(((size_t)e * TPRED + t) * 6 + l) * 64 + lane] = fmaxf(sk, 0.0f);
      sx[wid][64 + lane] = xn;
      if (l < 5 && t + d <= 23) ring[wid][(roff + (t & msk)) * 64 + lane] = xn;
    }
  }
}

// ---------------------------------------------------------------------------
// Phase 2: y = relu( relu(sk) @ W5 + b5 ) @ W6 + b6  for 49152 rows.
// Classic 128x128-tile register-blocked fp32 GEMM (K=384), fused head.
// ---------------------------------------------------------------------------
__global__ __launch_bounds__(256, 2) void dec_phase2(
    const float* __restrict__ skbuf,   // [49152][384], already relu'd
    const float* __restrict__ W5,      // [384][128]
    const float* __restrict__ b5,      // [128]
    const float* __restrict__ W6,      // [128]
    const float* __restrict__ b6,      // [1]
    float* __restrict__ out)           // [49152]
{
  __shared__ float As[16][128];        // A^T tile: As[k][row]
  __shared__ float Bs[16][128];        // W5 tile:  Bs[k][col]
  __shared__ float red[128][17];

  const int tid = threadIdx.x;
  const int R0  = blockIdx.x * 128;
  const int tr  = tid >> 4;            // 16 row-groups of 8 rows
  const int tc  = tid & 15;            // 16 col-groups of 8 cols

  float acc[8][8];
  #pragma unroll
  for (int r = 0; r < 8; ++r)
    #pragma unroll
    for (int c = 0; c < 8; ++c) acc[r][c] = 0.0f;

  for (int kb = 0; kb < 384; kb += 16) {
    #pragma unroll
    for (int q = tid; q < 512; q += 256) {
      const int row = q >> 2, kc = (q & 3) * 4;
      const float4 v = *(const float4*)&skbuf[(size_t)(R0 + row) * 384 + kb + kc];
      As[kc + 0][row] = v.x; As[kc + 1][row] = v.y;
      As[kc + 2][row] = v.z; As[kc + 3][row] = v.w;
    }
    #pragma unroll
    for (int q = tid; q < 512; q += 256) {
      const int k = q >> 5, c4 = (q & 31) * 4;
      *(float4*)&Bs[k][c4] = *(const float4*)&W5[(size_t)(kb + k) * 128 + c4];
    }
    __syncthreads();

    #pragma unroll
    for (int k = 0; k < 16; ++k) {
      float av[8], bv[8];
      *(float4*)&av[0] = *(const float4*)&As[k][tr * 8];
      *(float4*)&av[4] = *(const float4*)&As[k][tr * 8 + 4];
      *(float4*)&bv[0] = *(const float4*)&Bs[k][tc * 8];
      *(float4*)&bv[4] = *(const float4*)&Bs[k][tc * 8 + 4];
      #pragma unroll
      for (int r = 0; r < 8; ++r)
        #pragma unroll
        for (int c = 0; c < 8; ++c) acc[r][c] += av[r] * bv[c];
    }
    __syncthreads();
  }

  // fused head: h = relu(acc + b5), partial y = h @ W6
  float py[8];
  #pragma unroll
  for (int r = 0; r < 8; ++r) py[r] = 0.0f;
  #pragma unroll
  for (int c = 0; c < 8; ++c) {
    const float w6 = W6[tc * 8 + c];
    const float bb = b5[tc * 8 + c];
    #pragma unroll
    for (int r = 0; r < 8; ++r) py[r] += fmaxf(acc[r][c] + bb, 0.0f) * w6;
  }
  #pragma unroll
  for (int r = 0; r < 8; ++r) red[tr * 8 + r][tc] = py[r];
  __syncthreads();

  if (tid < 128) {
    float y = b6[0];
    #pragma unroll
    for (int c = 0; c < 16; ++c) y += red[tid][c];
    out[R0 + tid] = y;
  }
}

extern "C" void kernel_launch(void* const* d_in, const int* in_sizes, int n_in,
                              void* d_out, int out_size, void* d_ws, size_t ws_size,
                              hipStream_t stream) {
  const float* feat  = (const float*)d_in[0];
  const float* dinit = (const float*)d_in[1];
  const float* enc   = (const float*)d_in[2];
  const float* W1    = (const float*)d_in[3];
  const float* b1    = (const float*)d_in[4];
  const float* W2    = (const float*)d_in[5];
  const float* b2    = (const float*)d_in[6];
  const float* W3    = (const float*)d_in[7];
  const float* W4    = (const float*)d_in[8];
  const float* b4    = (const float*)d_in[9];
  const float* W5    = (const float*)d_in[10];
  const float* b5    = (const float*)d_in[11];
  const float* W6    = (const float*)d_in[12];
  const float* b6    = (const float*)d_in[13];

  float* out   = (float*)d_out;
  float* skbuf = (float*)d_ws;   // needs 49152*384*4 = 75.5 MB of workspace

  dec_phase1<<<dim3(256), dim3(512), 0, stream>>>(
      feat, dinit, enc, W1, b1, W2, b2, W3, W4, b4, skbuf, TPRED, 6);
  dec_phase2<<<dim3(384), dim3(256), 0, stream>>>(
      skbuf, W5, b5, W6, b6, out);
}

// Round 4
// 340.713 us; speedup vs baseline: 12.2323x; 12.2323x over previous
//
#include <hip/hip_runtime.h>
#include <hip/hip_bf16.h>
#include <cstddef>

#define NB 2048
#define TENC 168
#define TPRED 24

typedef _Float16 h8 __attribute__((ext_vector_type(8)));
typedef float f4v __attribute__((ext_vector_type(4)));

// ---------------------------------------------------------------------------
// Phase 1 (round 4): MFMA-f16 recurrent decoder.
// 128 blocks x 512 threads; block owns 16 batch elements (MFMA M=16).
// Wave w (0..7) owns output-column strip cols 16w..16w+15 for BOTH GEMMs:
//   dc[128] strips: w<4 -> f-half, w>=4 -> g-half.
// Weights live in per-lane VGPR B-fragments, loaded once (k = kk*32+q*8+j for
// elem j of K-step kk; the same mapping is used for A-frags, so any HW k-order
// is consistent). C/D layout: col=lane&15, row=(lane>>4)*4+reg (verified).
// State: xf32 (fp32 master) + xf16 (MFMA operand); dilation rings in f16 LDS,
// enc tails preloaded for l<=3; l=4 (t<16) and l=5 read enc from global.
// ---------------------------------------------------------------------------
__global__ __launch_bounds__(512, 1) void dec_phase1(
    const float* __restrict__ feat,    // [2048][24][15]
    const float* __restrict__ dinit,   // [2048][1]
    const float* __restrict__ enc,     // [6][2048][168][64]
    const float* __restrict__ W1,      // [16][64]
    const float* __restrict__ b1,      // [64]
    const float* __restrict__ W2,      // [64][128]
    const float* __restrict__ b2,      // [128]
    const float* __restrict__ W3,      // [64][128]
    const float* __restrict__ W4,      // [64][128]
    const float* __restrict__ b4,      // [128]
    float* __restrict__ skbuf,         // [2048*24][384]
    int t_steps, int n_layers)         // runtime 24, 6: blocks full unroll
{
  // rings: slots 0:(l0) 1-2:(l1) 3-6:(l2) 7-14:(l3) 15-22:(l4). 72 = 64+8 pad.
  __shared__ _Float16 ring[23][16][72];  // 53.0 KB
  __shared__ _Float16 xf16[16][72];      // 2.3 KB
  __shared__ _Float16 g16v[16][72];      // 2.3 KB
  __shared__ float    xf32[16][68];      // 4.3 KB
  __shared__ float    Fex[64][20];       // 5.1 KB  [dc-col][el], pad 20
  __shared__ float    Gex[64][20];       // 5.1 KB

  const int tid  = threadIdx.x;
  const int w    = tid >> 6;
  const int ln   = tid & 63;
  const int i    = ln & 15;      // M-row (element) for A/C; N-col within strip for B
  const int q    = ln >> 4;      // k-group
  const int e0   = blockIdx.x * 16;
  const int colw = 16 * w + i;   // this lane's output column (dc and out GEMMs)

  // ---- persistent weight B-fragments (consistent-kappa loading) ----
  h8 Bw23[4], Bw4[2];
  #pragma unroll
  for (int kk = 0; kk < 4; ++kk)
    #pragma unroll
    for (int j = 0; j < 8; ++j) {
      const int k = kk * 32 + q * 8 + j;
      const float v = (k < 64) ? W2[k * 128 + colw] : W3[(k - 64) * 128 + colw];
      Bw23[kk][j] = (_Float16)v;
    }
  #pragma unroll
  for (int kk = 0; kk < 2; ++kk)
    #pragma unroll
    for (int j = 0; j < 8; ++j) {
      const int k = kk * 32 + q * 8 + j;
      Bw4[kk][j] = (_Float16)W4[k * 128 + colw];
    }
  const float b2r = b2[colw];
  const float b4r = b4[colw];

  // x-embedding weights: lane = column
  float w1r[16];
  #pragma unroll
  for (int ii = 0; ii < 16; ++ii) w1r[ii] = W1[ii * 64 + ln];
  const float b1r = b1[ln];

  // ---- preload rings for l<=3 with encoder tails ----
  for (int idx = tid; idx < 1920; idx += 512) {
    const int c = idx & 7, el = (idx >> 3) & 15, s = idx >> 7;  // s = 0..14
    int l, j;
    if (s == 0)      { l = 0; j = 0; }
    else if (s < 3)  { l = 1; j = s - 1; }
    else if (s < 7)  { l = 2; j = s - 3; }
    else             { l = 3; j = s - 7; }
    const int d = 1 << l;
    const float* ep = enc + (((size_t)l * NB + e0 + el) * TENC + (TENC + j - d)) * 64 + c * 8;
    h8 hv;
    #pragma unroll
    for (int u = 0; u < 8; ++u) hv[u] = (_Float16)ep[u];
    *(h8*)&ring[s][el][c * 8] = hv;
  }
  __syncthreads();

  for (int t = 0; t < t_steps; ++t) {
    // ---- x = tanh([init, feat_t] @ W1 + b1); wave w computes elements 2w,2w+1
    #pragma unroll
    for (int s = 0; s < 2; ++s) {
      const int el = 2 * w + s;
      const int ee = e0 + el;
      const float ini = dinit[ee];
      const float* fp = feat + ((size_t)ee * TPRED + t) * 15;
      float u = b1r + ini * w1r[0];
      #pragma unroll
      for (int ii = 0; ii < 15; ++ii) u += fp[ii] * w1r[ii + 1];
      const float xv = tanhf(u);
      xf32[el][ln] = xv;
      xf16[el][ln] = (_Float16)xv;
    }
    __syncthreads();

    for (int l = 0; l < n_layers; ++l) {
      const int d = 1 << l;

      // ---- A-fragments for dc: [state | x], k = kk*32 + q*8 + j ----
      h8 a0, a1;
      if (l >= 4 && t < d) {
        // state directly from encoder (l=4 t<16; l=5 always)
        const float* ep = enc + (((size_t)l * NB + e0 + i) * TENC + (TENC + t - d)) * 64 + q * 8;
        const f4v u0 = *(const f4v*)(ep);
        const f4v u1 = *(const f4v*)(ep + 4);
        const f4v u2 = *(const f4v*)(ep + 32);
        const f4v u3 = *(const f4v*)(ep + 36);
        #pragma unroll
        for (int u = 0; u < 4; ++u) {
          a0[u] = (_Float16)u0[u]; a0[u + 4] = (_Float16)u1[u];
          a1[u] = (_Float16)u2[u]; a1[u + 4] = (_Float16)u3[u];
        }
      } else {
        const int slot = (l <= 3) ? (d - 1) + (t & (d - 1)) : 15 + (t & 7);
        const _Float16* rp = &ring[slot][i][0];
        a0 = *(const h8*)(rp + q * 8);
        a1 = *(const h8*)(rp + 32 + q * 8);
      }
      const h8 a2 = *(const h8*)&xf16[i][q * 8];
      const h8 a3 = *(const h8*)&xf16[i][32 + q * 8];

      // ---- dc strip = A @ W23[:,strip] + b2 ----
      f4v facc = {0.f, 0.f, 0.f, 0.f};
      facc = __builtin_amdgcn_mfma_f32_16x16x32_f16(a0, Bw23[0], facc, 0, 0, 0);
      facc = __builtin_amdgcn_mfma_f32_16x16x32_f16(a1, Bw23[1], facc, 0, 0, 0);
      facc = __builtin_amdgcn_mfma_f32_16x16x32_f16(a2, Bw23[2], facc, 0, 0, 0);
      facc = __builtin_amdgcn_mfma_f32_16x16x32_f16(a3, Bw23[3], facc, 0, 0, 0);
      #pragma unroll
      for (int r = 0; r < 4; ++r) facc[r] += b2r;

      if (w < 4) *(f4v*)&Fex[colw][4 * q] = facc;        // f-half, cols 0..63
      else       *(f4v*)&Gex[colw - 64][4 * q] = facc;   // g-half
      __syncthreads();

      // ---- gated = tanh(f) * sigmoid(g), write as [el][k] f16 ----
      if (ln < 32) {
        const int gcol = 8 * w + (ln & 7);
        const int el0  = (ln >> 3) * 4;
        const f4v fv = *(const f4v*)&Fex[gcol][el0];
        const f4v gv = *(const f4v*)&Gex[gcol][el0];
        #pragma unroll
        for (int r = 0; r < 4; ++r) {
          const float gd = tanhf(fv[r]) * (1.0f / (1.0f + __expf(-gv[r])));
          g16v[el0 + r][gcol] = (_Float16)gd;
        }
      }
      __syncthreads();

      // ---- out strip = gated @ W4[:,strip] + b4 ----
      const h8 p0 = *(const h8*)&g16v[i][q * 8];
      const h8 p1 = *(const h8*)&g16v[i][32 + q * 8];
      f4v oacc = {0.f, 0.f, 0.f, 0.f};
      oacc = __builtin_amdgcn_mfma_f32_16x16x32_f16(p0, Bw4[0], oacc, 0, 0, 0);
      oacc = __builtin_amdgcn_mfma_f32_16x16x32_f16(p1, Bw4[1], oacc, 0, 0, 0);
      #pragma unroll
      for (int r = 0; r < 4; ++r) oacc[r] += b4r;

      if (w < 4) {
        // skip columns 0..63: relu -> skbuf
        #pragma unroll
        for (int r = 0; r < 4; ++r) {
          skbuf[(((size_t)(e0 + 4 * q + r)) * TPRED + t) * 384 + l * 64 + colw] =
              fmaxf(oacc[r], 0.0f);
        }
      } else {
        // res columns: x += res; refresh xf32/xf16/ring
        const int c = colw - 64;
        const int slot = (l <= 3) ? (d - 1) + (t & (d - 1)) : 15 + (t & 7);
        const bool wr = (l < 5) && (t + d <= 23);
        #pragma unroll
        for (int r = 0; r < 4; ++r) {
          const int el = 4 * q + r;
          const float xn = xf32[el][c] + oacc[r];
          xf32[el][c] = xn;
          xf16[el][c] = (_Float16)xn;
          if (wr) ring[slot][el][c] = (_Float16)xn;
        }
      }
      __syncthreads();
    }
  }
}

// ---------------------------------------------------------------------------
// Phase 2: y = relu( relu(sk) @ W5 + b5 ) @ W6 + b6  for 49152 rows. (fp32)
// ---------------------------------------------------------------------------
__global__ __launch_bounds__(256, 2) void dec_phase2(
    const float* __restrict__ skbuf,   // [49152][384], already relu'd
    const float* __restrict__ W5,      // [384][128]
    const float* __restrict__ b5,      // [128]
    const float* __restrict__ W6,      // [128]
    const float* __restrict__ b6,      // [1]
    float* __restrict__ out)           // [49152]
{
  __shared__ float As[16][128];
  __shared__ float Bs[16][128];
  __shared__ float red[128][17];

  const int tid = threadIdx.x;
  const int R0  = blockIdx.x * 128;
  const int tr  = tid >> 4;
  const int tc  = tid & 15;

  float acc[8][8];
  #pragma unroll
  for (int r = 0; r < 8; ++r)
    #pragma unroll
    for (int c = 0; c < 8; ++c) acc[r][c] = 0.0f;

  for (int kb = 0; kb < 384; kb += 16) {
    #pragma unroll
    for (int qq = tid; qq < 512; qq += 256) {
      const int row = qq >> 2, kc = (qq & 3) * 4;
      const float4 v = *(const float4*)&skbuf[(size_t)(R0 + row) * 384 + kb + kc];
      As[kc + 0][row] = v.x; As[kc + 1][row] = v.y;
      As[kc + 2][row] = v.z; As[kc + 3][row] = v.w;
    }
    #pragma unroll
    for (int qq = tid; qq < 512; qq += 256) {
      const int k = qq >> 5, c4 = (qq & 31) * 4;
      *(float4*)&Bs[k][c4] = *(const float4*)&W5[(size_t)(kb + k) * 128 + c4];
    }
    __syncthreads();

    #pragma unroll
    for (int k = 0; k < 16; ++k) {
      float av[8], bv[8];
      *(float4*)&av[0] = *(const float4*)&As[k][tr * 8];
      *(float4*)&av[4] = *(const float4*)&As[k][tr * 8 + 4];
      *(float4*)&bv[0] = *(const float4*)&Bs[k][tc * 8];
      *(float4*)&bv[4] = *(const float4*)&Bs[k][tc * 8 + 4];
      #pragma unroll
      for (int r = 0; r < 8; ++r)
        #pragma unroll
        for (int c = 0; c < 8; ++c) acc[r][c] += av[r] * bv[c];
    }
    __syncthreads();
  }

  float py[8];
  #pragma unroll
  for (int r = 0; r < 8; ++r) py[r] = 0.0f;
  #pragma unroll
  for (int c = 0; c < 8; ++c) {
    const float w6 = W6[tc * 8 + c];
    const float bb = b5[tc * 8 + c];
    #pragma unroll
    for (int r = 0; r < 8; ++r) py[r] += fmaxf(acc[r][c] + bb, 0.0f) * w6;
  }
  #pragma unroll
  for (int r = 0; r < 8; ++r) red[tr * 8 + r][tc] = py[r];
  __syncthreads();

  if (tid < 128) {
    float y = b6[0];
    #pragma unroll
    for (int c = 0; c < 16; ++c) y += red[tid][c];
    out[R0 + tid] = y;
  }
}

extern "C" void kernel_launch(void* const* d_in, const int* in_sizes, int n_in,
                              void* d_out, int out_size, void* d_ws, size_t ws_size,
                              hipStream_t stream) {
  const float* feat  = (const float*)d_in[0];
  const float* dinit = (const float*)d_in[1];
  const float* enc   = (const float*)d_in[2];
  const float* W1    = (const float*)d_in[3];
  const float* b1    = (const float*)d_in[4];
  const float* W2    = (const float*)d_in[5];
  const float* b2    = (const float*)d_in[6];
  const float* W3    = (const float*)d_in[7];
  const float* W4    = (const float*)d_in[8];
  const float* b4    = (const float*)d_in[9];
  const float* W5    = (const float*)d_in[10];
  const float* b5    = (const float*)d_in[11];
  const float* W6    = (const float*)d_in[12];
  const float* b6    = (const float*)d_in[13];

  float* out   = (float*)d_out;
  float* skbuf = (float*)d_ws;   // 49152*384*4 = 75.5 MB workspace

  dec_phase1<<<dim3(128), dim3(512), 0, stream>>>(
      feat, dinit, enc, W1, b1, W2, b2, W3, W4, b4, skbuf, TPRED, 6);
  dec_phase2<<<dim3(384), dim3(256), 0, stream>>>(
      skbuf, W5, b5, W6, b6, out);
}

// Round 5
// 159.068 us; speedup vs baseline: 26.2008x; 2.1419x over previous
//
#include <hip/hip_runtime.h>
#include <hip/hip_bf16.h>
#include <cstddef>

#define NB 2048
#define TENC 168
#define TPRED 24

typedef _Float16 h8 __attribute__((ext_vector_type(8)));
typedef float f4v __attribute__((ext_vector_type(4)));

// LDS-only barrier: waits DS ops, does NOT drain vmcnt -> global loads/stores
// stay in flight across it (T4 discipline). Single asm block so the "memory"
// clobber fences the compiler on both sides of s_barrier.
#define LBAR() asm volatile("s_waitcnt lgkmcnt(0)\ns_barrier" ::: "memory")

__device__ __forceinline__ float tanh_fast(float v) {
  v = fminf(v, 15.0f);                       // avoid inf/inf NaN; tanh(15)==1 in f32
  const float ex = __expf(2.0f * v);
  return (ex - 1.0f) * __builtin_amdgcn_rcpf(ex + 1.0f);
}
__device__ __forceinline__ float sig_fast(float v) {
  return __builtin_amdgcn_rcpf(1.0f + __expf(-v));   // saturates correctly at +-inf
}

// ---------------------------------------------------------------------------
// Phase 1: MFMA-f16 recurrent decoder. 128 blocks x 512 threads (8 waves),
// block owns 16 batch elements (MFMA M=16).
// dc GEMM: wave w computes f-strip (w&3) AND paired g-strip (w&3)+4 so
// gated = tanh(f)*sigmoid(g) is in-lane (col pairing c, c+64). Waves 4-7
// duplicate nothing: they skip dc entirely and only run the out GEMM strips.
// out GEMM: wave w owns strip w (cols 16w..16w+15): w<4 -> skips (f16 global),
// w>=4 -> res -> x update (x carried in registers across layers).
// Barriers: 2 LBARs per layer-step, no vmcnt drains anywhere in the loop.
// enc slices for l=4 (t<16) and l=5 prefetched into regs at t-step top.
// k-mapping k = kk*32 + q*8 + j used consistently for A and B in all GEMMs.
// C/D layout: col = lane&15, row = (lane>>4)*4 + reg (verified m89).
// ---------------------------------------------------------------------------
__global__ __launch_bounds__(512, 1) void dec_phase1(
    const float* __restrict__ feat,    // [2048][24][15]
    const float* __restrict__ dinit,   // [2048][1]
    const float* __restrict__ enc,     // [6][2048][168][64]
    const float* __restrict__ W1,      // [16][64]
    const float* __restrict__ b1,      // [64]
    const float* __restrict__ W2,      // [64][128]
    const float* __restrict__ b2,      // [128]
    const float* __restrict__ W3,      // [64][128]
    const float* __restrict__ W4,      // [64][128]
    const float* __restrict__ b4,      // [128]
    _Float16* __restrict__ skbuf,      // [2048*24][384] f16
    int t_steps, int n_layers)         // runtime 24, 6: blocks full unroll
{
  // rings: slots 0:(l0) 1-2:(l1) 3-6:(l2) 7-14:(l3) 15-22:(l4 x-history)
  __shared__ _Float16 ring[23][16][72];  // 53.0 KB
  __shared__ _Float16 xf16[16][72];      // 2.3 KB  [el][k]
  __shared__ _Float16 g16v[16][72];      // 2.3 KB  [el][k]
  __shared__ float    xf32[64][20];      // 5.1 KB  [c][el] (embed -> l0 handoff)

  const int tid = threadIdx.x;
  const int w   = tid >> 6;
  const int ln  = tid & 63;
  const int i   = ln & 15;
  const int q   = ln >> 4;
  const int e0  = blockIdx.x * 16;
  const int fs  = w & 3;
  const int cf  = 16 * fs + i;        // f column (0..63)
  const int cg  = 64 + cf;            // paired g column
  const int co  = 16 * w + i;         // out column (0..127)
  const int cres = co - 64;           // res column for w>=4

  // ---- persistent weight B-fragments ----
  h8 Bf[4], Bg[4], B4[2];
  #pragma unroll
  for (int kk = 0; kk < 4; ++kk)
    #pragma unroll
    for (int j = 0; j < 8; ++j) {
      const int k = kk * 32 + q * 8 + j;
      Bf[kk][j] = (_Float16)((k < 64) ? W2[k * 128 + cf] : W3[(k - 64) * 128 + cf]);
      Bg[kk][j] = (_Float16)((k < 64) ? W2[k * 128 + cg] : W3[(k - 64) * 128 + cg]);
    }
  #pragma unroll
  for (int kk = 0; kk < 2; ++kk)
    #pragma unroll
    for (int j = 0; j < 8; ++j)
      B4[kk][j] = (_Float16)W4[(kk * 32 + q * 8 + j) * 128 + co];
  const float b2f = b2[cf], b2g = b2[cg], b4r = b4[co];

  float w1r[16];
  #pragma unroll
  for (int ii = 0; ii < 16; ++ii) w1r[ii] = W1[ii * 64 + ln];
  const float b1r  = b1[ln];
  const float ini0 = dinit[e0 + 2 * w];
  const float ini1 = dinit[e0 + 2 * w + 1];

  // ---- preload rings for l<=3 with encoder tails ----
  for (int idx = tid; idx < 1920; idx += 512) {
    const int c = idx & 7, el = (idx >> 3) & 15, s = idx >> 7;
    int l, j;
    if (s == 0)      { l = 0; j = 0; }
    else if (s < 3)  { l = 1; j = s - 1; }
    else if (s < 7)  { l = 2; j = s - 3; }
    else             { l = 3; j = s - 7; }
    const int d = 1 << l;
    const float* ep = enc + (((size_t)l * NB + e0 + el) * TENC + (TENC + j - d)) * 64 + c * 8;
    h8 hv;
    #pragma unroll
    for (int u = 0; u < 8; ++u) hv[u] = (_Float16)ep[u];
    *(h8*)&ring[s][el][c * 8] = hv;
  }
  __syncthreads();

  // ---- x-embed for t=0 ----
  #pragma unroll
  for (int s = 0; s < 2; ++s) {
    const int el = 2 * w + s;
    const float* fp = feat + ((size_t)(e0 + el) * TPRED + 0) * 15;
    float u = b1r + (s ? ini1 : ini0) * w1r[0];
    #pragma unroll
    for (int ii = 0; ii < 15; ++ii) u += fp[ii] * w1r[ii + 1];
    const float xv = tanh_fast(u);
    xf16[el][ln] = (_Float16)xv;
    xf32[ln][el] = xv;
  }
  LBAR();

  for (int t = 0; t < t_steps; ++t) {
    // ---- prefetch enc state slices for l=4 (t<16) and l=5 into regs ----
    float4 p4a, p4b, p4c, p4d, p5a, p5b, p5c, p5d;
    if (w < 4) {
      const int t4 = (t < 16) ? t : 15;   // clamp: value unused when t>=16
      const float* e4 = enc + (((size_t)4 * NB + e0 + i) * TENC + (152 + t4)) * 64 + q * 8;
      const float* e5 = enc + (((size_t)5 * NB + e0 + i) * TENC + (136 + t )) * 64 + q * 8;
      p4a = *(const float4*)(e4);      p4b = *(const float4*)(e4 + 4);
      p4c = *(const float4*)(e4 + 32); p4d = *(const float4*)(e4 + 36);
      p5a = *(const float4*)(e5);      p5b = *(const float4*)(e5 + 4);
      p5c = *(const float4*)(e5 + 32); p5d = *(const float4*)(e5 + 36);
    }

    f4v xreg = {0.f, 0.f, 0.f, 0.f};     // w>=4: x[el=4q+r][cres], carried l0->l5

    for (int l = 0; l < n_layers; ++l) {
      const int d    = 1 << l;
      const int slot = (l <= 3) ? (d - 1) + (t & (d - 1)) : 15 + (t & 7);

      if (w < 4) {
        // ---- dc A-fragments ----
        h8 a0, a1;
        if (l >= 4 && t < d) {
          float4 sa, sb, sc, sd;
          if (l == 4) { sa = p4a; sb = p4b; sc = p4c; sd = p4d; }
          else        { sa = p5a; sb = p5b; sc = p5c; sd = p5d; }
          #pragma unroll
          for (int u = 0; u < 4; ++u) {
            a0[u] = (_Float16)sa[u]; a0[u + 4] = (_Float16)sb[u];
            a1[u] = (_Float16)sc[u]; a1[u + 4] = (_Float16)sd[u];
          }
        } else {
          a0 = *(const h8*)&ring[slot][i][q * 8];
          a1 = *(const h8*)&ring[slot][i][32 + q * 8];
        }
        const h8 a2 = *(const h8*)&xf16[i][q * 8];
        const h8 a3 = *(const h8*)&xf16[i][32 + q * 8];

        // ---- paired dc strips: f and g in the same lane ----
        f4v fa = {0.f, 0.f, 0.f, 0.f}, ga = {0.f, 0.f, 0.f, 0.f};
        fa = __builtin_amdgcn_mfma_f32_16x16x32_f16(a0, Bf[0], fa, 0, 0, 0);
        ga = __builtin_amdgcn_mfma_f32_16x16x32_f16(a0, Bg[0], ga, 0, 0, 0);
        fa = __builtin_amdgcn_mfma_f32_16x16x32_f16(a1, Bf[1], fa, 0, 0, 0);
        ga = __builtin_amdgcn_mfma_f32_16x16x32_f16(a1, Bg[1], ga, 0, 0, 0);
        fa = __builtin_amdgcn_mfma_f32_16x16x32_f16(a2, Bf[2], fa, 0, 0, 0);
        ga = __builtin_amdgcn_mfma_f32_16x16x32_f16(a2, Bg[2], ga, 0, 0, 0);
        fa = __builtin_amdgcn_mfma_f32_16x16x32_f16(a3, Bf[3], fa, 0, 0, 0);
        ga = __builtin_amdgcn_mfma_f32_16x16x32_f16(a3, Bg[3], ga, 0, 0, 0);

        #pragma unroll
        for (int r = 0; r < 4; ++r) {
          const float gd = tanh_fast(fa[r] + b2f) * sig_fast(ga[r] + b2g);
          g16v[4 * q + r][cf] = (_Float16)gd;
        }
      }
      LBAR();   // barrier A: gated visible to all waves

      // ---- out strip = gated @ W4[:,strip] ----
      const h8 p0 = *(const h8*)&g16v[i][q * 8];
      const h8 p1 = *(const h8*)&g16v[i][32 + q * 8];
      f4v oa = {0.f, 0.f, 0.f, 0.f};
      oa = __builtin_amdgcn_mfma_f32_16x16x32_f16(p0, B4[0], oa, 0, 0, 0);
      oa = __builtin_amdgcn_mfma_f32_16x16x32_f16(p1, B4[1], oa, 0, 0, 0);

      if (w < 4) {
        // skip half: relu -> f16 global store (stays in flight across LBARs)
        #pragma unroll
        for (int r = 0; r < 4; ++r) {
          const float sk = fmaxf(oa[r] + b4r, 0.0f);
          skbuf[((size_t)(e0 + 4 * q + r) * TPRED + t) * 384 + l * 64 + co] =
              (_Float16)sk;
        }
      } else if (l + 1 < n_layers) {
        // res half: x update (l=5's res is dead -> skipped)
        if (l == 0) xreg = *(const f4v*)&xf32[cres][4 * q];
        const bool wr = (t + d <= 23);
        #pragma unroll
        for (int r = 0; r < 4; ++r) {
          const float xn = xreg[r] + (oa[r] + b4r);
          xreg[r] = xn;
          xf16[4 * q + r][cres] = (_Float16)xn;
          if (wr) ring[slot][4 * q + r][cres] = (_Float16)xn;
        }
      }

      if (l + 1 == n_layers && t + 1 < t_steps) {
        // x-embed for t+1 in layer 5's shadow (old xf16 fully consumed)
        #pragma unroll
        for (int s = 0; s < 2; ++s) {
          const int el = 2 * w + s;
          const float* fp = feat + ((size_t)(e0 + el) * TPRED + (t + 1)) * 15;
          float u = b1r + (s ? ini1 : ini0) * w1r[0];
          #pragma unroll
          for (int ii = 0; ii < 15; ++ii) u += fp[ii] * w1r[ii + 1];
          const float xv = tanh_fast(u);
          xf16[el][ln] = (_Float16)xv;
          xf32[ln][el] = xv;
        }
      }
      LBAR();   // barrier B: x/ring/embed visible for next layer/step
    }
  }
}

// ---------------------------------------------------------------------------
// Phase 2: y = relu( sk @ W5 + b5 ) @ W6 + b6, 49152 rows, f16 MFMA.
// 384 blocks x 512 threads; A tile (128 rows x 384) staged once in LDS;
// wave w owns N-strip cols 16w..16w+15, W5 B-frags in VGPR (12 x h8);
// W6 head fused via in-wave shuffle reduce + tiny LDS cross-wave reduce.
// ---------------------------------------------------------------------------
__global__ __launch_bounds__(512, 1) void dec_phase2(
    const _Float16* __restrict__ skbuf,  // [49152][384] f16 (already relu'd)
    const float* __restrict__ W5,        // [384][128]
    const float* __restrict__ b5,        // [128]
    const float* __restrict__ W6,        // [128]
    const float* __restrict__ b6,        // [1]
    float* __restrict__ out)             // [49152]
{
  __shared__ _Float16 As[128][392];      // 100.4 KB (392: 16B-aligned rows, few banks off)
  __shared__ float red[128][8];          // 4 KB

  const int tid = threadIdx.x;
  const int w   = tid >> 6;
  const int ln  = tid & 63;
  const int i   = ln & 15;
  const int q   = ln >> 4;
  const int R0  = blockIdx.x * 128;
  const int col = 16 * w + i;

  // W5 B-fragments for this wave's strip
  h8 B5[12];
  #pragma unroll
  for (int kk = 0; kk < 12; ++kk)
    #pragma unroll
    for (int j = 0; j < 8; ++j)
      B5[kk][j] = (_Float16)W5[(size_t)(kk * 32 + q * 8 + j) * 128 + col];
  const float b5r = b5[col], w6r = W6[col];

  // stage A: 128 rows x 384 f16 = 96 KB
  #pragma unroll
  for (int it = 0; it < 12; ++it) {
    const int idx = tid + it * 512;            // 0..6143
    const int row = idx / 48, seg = idx % 48;
    const h8 v = *(const h8*)&skbuf[(size_t)(R0 + row) * 384 + seg * 8];
    *(h8*)&As[row][seg * 8] = v;
  }
  __syncthreads();

  #pragma unroll
  for (int m = 0; m < 8; ++m) {
    f4v acc = {0.f, 0.f, 0.f, 0.f};
    #pragma unroll
    for (int kk = 0; kk < 12; ++kk) {
      const h8 a = *(const h8*)&As[16 * m + i][kk * 32 + q * 8];
      acc = __builtin_amdgcn_mfma_f32_16x16x32_f16(a, B5[kk], acc, 0, 0, 0);
    }
    float py[4];
    #pragma unroll
    for (int r = 0; r < 4; ++r)
      py[r] = fmaxf(acc[r] + b5r, 0.0f) * w6r;
    // reduce over the 16 cols of this strip (lanes share q-group)
    #pragma unroll
    for (int r = 0; r < 4; ++r) {
      float v = py[r];
      v += __shfl_xor(v, 1);
      v += __shfl_xor(v, 2);
      v += __shfl_xor(v, 4);
      v += __shfl_xor(v, 8);
      py[r] = v;
    }
    if (i == 0) {
      #pragma unroll
      for (int r = 0; r < 4; ++r) red[16 * m + 4 * q + r][w] = py[r];
    }
  }
  __syncthreads();

  if (tid < 128) {
    const f4v r0 = *(const f4v*)&red[tid][0];
    const f4v r1 = *(const f4v*)&red[tid][4];
    out[R0 + tid] = b6[0] + r0[0] + r0[1] + r0[2] + r0[3]
                          + r1[0] + r1[1] + r1[2] + r1[3];
  }
}

extern "C" void kernel_launch(void* const* d_in, const int* in_sizes, int n_in,
                              void* d_out, int out_size, void* d_ws, size_t ws_size,
                              hipStream_t stream) {
  const float* feat  = (const float*)d_in[0];
  const float* dinit = (const float*)d_in[1];
  const float* enc   = (const float*)d_in[2];
  const float* W1    = (const float*)d_in[3];
  const float* b1    = (const float*)d_in[4];
  const float* W2    = (const float*)d_in[5];
  const float* b2    = (const float*)d_in[6];
  const float* W3    = (const float*)d_in[7];
  const float* W4    = (const float*)d_in[8];
  const float* b4    = (const float*)d_in[9];
  const float* W5    = (const float*)d_in[10];
  const float* b5    = (const float*)d_in[11];
  const float* W6    = (const float*)d_in[12];
  const float* b6    = (const float*)d_in[13];

  float*     out   = (float*)d_out;
  _Float16*  skbuf = (_Float16*)d_ws;   // 49152*384*2 = 37.7 MB workspace

  dec_phase1<<<dim3(128), dim3(512), 0, stream>>>(
      feat, dinit, enc, W1, b1, W2, b2, W3, W4, b4, skbuf, TPRED, 6);
  dec_phase2<<<dim3(384), dim3(512), 0, stream>>>(
      skbuf, W5, b5, W6, b6, out);
}

// Round 6
// 117.704 us; speedup vs baseline: 35.4082x; 1.3514x over previous
//
#include <hip/hip_runtime.h>
#include <hip/hip_bf16.h>
#include <cstddef>

#define NB 2048
#define TENC 168
#define TPRED 24

typedef _Float16 h8 __attribute__((ext_vector_type(8)));
typedef float f4v __attribute__((ext_vector_type(4)));

// LDS-only barrier: waits DS ops, does NOT drain vmcnt (global loads/stores
// stay in flight across it).
#define LBAR() asm volatile("s_waitcnt lgkmcnt(0)\ns_barrier" ::: "memory")

__device__ __forceinline__ float tanh_fast(float v) {
  v = fminf(v, 15.0f);
  const float ex = __expf(2.0f * v);
  return (ex - 1.0f) * __builtin_amdgcn_rcpf(ex + 1.0f);
}
__device__ __forceinline__ float sig_fast(float v) {
  return __builtin_amdgcn_rcpf(1.0f + __expf(-v));
}

#define MFMA16(a, b, c) __builtin_amdgcn_mfma_f32_16x16x32_f16((a), (b), (c), 0, 0, 0)

// ---------------------------------------------------------------------------
// Phase 1 (round 6): critical-path-shortened recurrent decoder.
// Key identity: x_{l+1}@W3 = x_l@W3 + gated_l@(W4res@W3). Carrying Z = x@W3
// as an f32 accumulator makes the recurrence: gated_l -> (LDS exchange) ->
// Z += gated@W43 -> dc = Z + state@W2 + b2 -> gated_{l+1}. The out-GEMM,
// x materialization, ring and skbuf writes run ONE INTERVAL BEHIND on waves
// 4-7 (g16v double-buffered by layer parity). One barrier per layer.
// Waves 0-3: recurrence for f-strip (w&3) and paired g-strip +64.
// Waves 4-7: lagged out-GEMM; skip strip = res strip = cols 16(w-4)+i.
// All state (ring/enc) prefetched at step-top; feat prefetched a step ahead.
// W43 computed in an LDS prologue (f32 dots), stored f16, loaded as B-frags.
// k-mapping k = kk*32 + q*8 + j used consistently for all A and B frags.
// ---------------------------------------------------------------------------
__global__ __launch_bounds__(512, 1) void dec_phase1(
    const float* __restrict__ feat,    // [2048][24][15]
    const float* __restrict__ dinit,   // [2048][1]
    const float* __restrict__ enc,     // [6][2048][168][64]
    const float* __restrict__ W1,      // [16][64]
    const float* __restrict__ b1,      // [64]
    const float* __restrict__ W2,      // [64][128]
    const float* __restrict__ b2,      // [128]
    const float* __restrict__ W3,      // [64][128]
    const float* __restrict__ W4,      // [64][128]
    const float* __restrict__ b4,      // [128]
    _Float16* __restrict__ skbuf,      // [2048*24][384] f16
    int t_steps)                       // runtime 24: blocks t-loop unroll
{
  __shared__ _Float16 ring[23][16][72];  // 52.9 KB  dilation rings / enc tails
  __shared__ _Float16 g16v[2][16][72];   // 4.6 KB   gated, parity dbuf
  __shared__ _Float16 xf16[16][72];      // 2.3 KB   x_0(t) for Z_0 MFMA
  __shared__ float    xf32[64][20];      // 5.1 KB   x_0(t) [col][el] for xreg
  __shared__ _Float16 W43h[64][136];     // 17.0 KB  W4res@W3 (f16)

  const int tid = threadIdx.x;
  const int w   = tid >> 6;
  const int ln  = tid & 63;
  const int i   = ln & 15;
  const int q   = ln >> 4;
  const int q8  = q * 8;
  const int e0  = blockIdx.x * 16;

  // -------- prologue: W43 = W4[:,64:128] @ W3  (stage f32 in ring region) ---
  float* W3s  = (float*)&ring[0][0][0];   // [64][128] 32 KB
  float* W4rs = W3s + 64 * 128;           // [64][64]  16 KB (total 48 <= 52.9)
  for (int idx = tid; idx < 2048; idx += 512)
    ((float4*)W3s)[idx] = ((const float4*)W3)[idx];
  for (int idx = tid; idx < 1024; idx += 512) {
    const int row = idx >> 4, seg = idx & 15;
    *(float4*)&W4rs[row * 64 + seg * 4] = *(const float4*)&W4[row * 128 + 64 + seg * 4];
  }
  __syncthreads();
  {
    const int c = tid & 127, k0 = (tid >> 7) << 4;
    float acc[16];
    #pragma unroll
    for (int r = 0; r < 16; ++r) acc[r] = 0.0f;
    for (int m = 0; m < 64; ++m) {
      const float w3v = W3s[m * 128 + c];          // 128 lanes stride-1: clean
      #pragma unroll
      for (int r = 0; r < 16; ++r) acc[r] += W4rs[(k0 + r) * 64 + m] * w3v;  // broadcast
    }
    #pragma unroll
    for (int r = 0; r < 16; ++r) W43h[k0 + r][c] = (_Float16)acc[r];
  }
  __syncthreads();   // W3s/W4rs dead; ring region reusable

  // -------- per-wave roles & weight fragments --------
  const int fs = w & 3;
  const int cf = 16 * fs + i;          // waves 0-3: f column
  const int cg = 64 + cf;              // paired g column
  const int cs = 16 * (w - 4) + i;     // waves 4-7: skip col == res col == x col

  h8 BW2f[2], BW2g[2], BW3f[2], BW3g[2], B43f[2], B43g[2], B4s[2], B4r[2];
  float b2f = 0.f, b2g = 0.f, b4s_b = 0.f, b4r_b = 0.f;
  if (w < 4) {
    #pragma unroll
    for (int kk = 0; kk < 2; ++kk)
      #pragma unroll
      for (int j = 0; j < 8; ++j) {
        const int k = kk * 32 + q8 + j;
        BW2f[kk][j] = (_Float16)W2[k * 128 + cf];
        BW2g[kk][j] = (_Float16)W2[k * 128 + cg];
        BW3f[kk][j] = (_Float16)W3[k * 128 + cf];
        BW3g[kk][j] = (_Float16)W3[k * 128 + cg];
        B43f[kk][j] = W43h[k][cf];
        B43g[kk][j] = W43h[k][cg];
      }
    b2f = b2[cf]; b2g = b2[cg];
  } else {
    #pragma unroll
    for (int kk = 0; kk < 2; ++kk)
      #pragma unroll
      for (int j = 0; j < 8; ++j) {
        const int k = kk * 32 + q8 + j;
        B4s[kk][j] = (_Float16)W4[k * 128 + cs];
        B4r[kk][j] = (_Float16)W4[k * 128 + 64 + cs];
      }
    b4s_b = b4[cs]; b4r_b = b4[64 + cs];
  }
  float w1r[16];
  #pragma unroll
  for (int ii = 0; ii < 16; ++ii) w1r[ii] = W1[ii * 64 + ln];
  const float b1r  = b1[ln];
  const float ini0 = dinit[e0 + 2 * w];
  const float ini1 = dinit[e0 + 2 * w + 1];

  // -------- ring preload (l<=3 encoder tails) --------
  for (int idx = tid; idx < 1920; idx += 512) {
    const int c = idx & 7, el = (idx >> 3) & 15, s = idx >> 7;
    int l, j;
    if (s == 0)      { l = 0; j = 0; }
    else if (s < 3)  { l = 1; j = s - 1; }
    else if (s < 7)  { l = 2; j = s - 3; }
    else             { l = 3; j = s - 7; }
    const int d = 1 << l;
    const float* ep = enc + (((size_t)l * NB + e0 + el) * TENC + (TENC + j - d)) * 64 + c * 8;
    h8 hv;
    #pragma unroll
    for (int u = 0; u < 8; ++u) hv[u] = (_Float16)ep[u];
    *(h8*)&ring[s][el][c * 8] = hv;
  }

  // -------- t=0 embed --------
  #pragma unroll
  for (int s = 0; s < 2; ++s) {
    const int el = 2 * w + s;
    const float* fp = feat + (size_t)(e0 + el) * TPRED * 15;
    float u = b1r + (s ? ini1 : ini0) * w1r[0];
    #pragma unroll
    for (int ii = 0; ii < 15; ++ii) u += fp[ii] * w1r[ii + 1];
    const float xv = tanh_fast(u);
    xf16[el][ln] = (_Float16)xv;
    xf32[ln][el] = xv;
  }
  LBAR();

  f4v Zf = {0,0,0,0}, Zg = {0,0,0,0}, xreg = {0,0,0,0};

  for (int t = 0; t < t_steps; ++t) {
    // ======== E (fused with L0) ========
    // feat prefetch for t+1
    const int tn = (t + 1 < t_steps) ? t + 1 : t;
    f4v pfa[2], pfb[2], pfc[2];
    float2 pfd[2]; float pfe[2];
    #pragma unroll
    for (int s = 0; s < 2; ++s) {
      const float* fp = feat + ((size_t)(e0 + 2 * w + s) * TPRED + tn) * 15;
      pfa[s] = *(const f4v*)(fp);
      pfb[s] = *(const f4v*)(fp + 4);
      pfc[s] = *(const f4v*)(fp + 8);
      pfd[s] = *(const float2*)(fp + 12);
      pfe[s] = fp[14];
    }

    h8 s0a[4], s1a[4], s4a0, s4a1;
    f4v p4[4], p5[4];
    if (w < 4) {
      const int t4 = (t < 16) ? t : 0;   // clamp; unused when t>=16
      const float* e4 = enc + (((size_t)4 * NB + e0 + i) * TENC + (152 + t4)) * 64 + q8;
      const float* e5 = enc + (((size_t)5 * NB + e0 + i) * TENC + (136 + t )) * 64 + q8;
      p4[0] = *(const f4v*)(e4);      p4[1] = *(const f4v*)(e4 + 4);
      p4[2] = *(const f4v*)(e4 + 32); p4[3] = *(const f4v*)(e4 + 36);
      p5[0] = *(const f4v*)(e5);      p5[1] = *(const f4v*)(e5 + 4);
      p5[2] = *(const f4v*)(e5 + 32); p5[3] = *(const f4v*)(e5 + 36);

      // ring-state prefetch, all layers (slots stable until lagged rewrite)
      #pragma unroll
      for (int l = 0; l < 4; ++l) {
        const int d = 1 << l;
        const int slot = (d - 1) + (t & (d - 1));
        s0a[l] = *(const h8*)&ring[slot][i][q8];
        s1a[l] = *(const h8*)&ring[slot][i][32 + q8];
      }
      {
        const int slot4 = 15 + (t & 7);
        s4a0 = *(const h8*)&ring[slot4][i][q8];      // garbage if t<16 (unused)
        s4a1 = *(const h8*)&ring[slot4][i][32 + q8];
      }

      // Z_0 = x_0 @ W3
      const h8 a2 = *(const h8*)&xf16[i][q8];
      const h8 a3 = *(const h8*)&xf16[i][32 + q8];
      Zf = (f4v){0,0,0,0};  Zg = (f4v){0,0,0,0};
      Zf = MFMA16(a2, BW3f[0], Zf); Zf = MFMA16(a3, BW3f[1], Zf);
      Zg = MFMA16(a2, BW3g[0], Zg); Zg = MFMA16(a3, BW3g[1], Zg);

      // ---- L(0): dc_0 = Z_0 + state_0@W2 + b2 ----
      f4v dcf = Zf, dcg = Zg;
      dcf = MFMA16(s0a[0], BW2f[0], dcf); dcf = MFMA16(s1a[0], BW2f[1], dcf);
      dcg = MFMA16(s0a[0], BW2g[0], dcg); dcg = MFMA16(s1a[0], BW2g[1], dcg);
      #pragma unroll
      for (int r = 0; r < 4; ++r) {
        const float gd = tanh_fast(dcf[r] + b2f) * sig_fast(dcg[r] + b2g);
        g16v[0][4 * q + r][cf] = (_Float16)gd;
      }
    } else {
      xreg = *(const f4v*)&xf32[cs][4 * q];   // x_0(t)
    }
    LBAR();

    // ======== L(1..5): compute gated_l; lagged out-work for l-1 ========
    #pragma unroll
    for (int l = 1; l < 6; ++l) {
      const int pm1 = (l - 1) & 1;
      const h8 gA0 = *(const h8*)&g16v[pm1][i][q8];
      const h8 gA1 = *(const h8*)&g16v[pm1][i][32 + q8];

      if (w < 4) {
        Zf = MFMA16(gA0, B43f[0], Zf); Zf = MFMA16(gA1, B43f[1], Zf);
        Zg = MFMA16(gA0, B43g[0], Zg); Zg = MFMA16(gA1, B43g[1], Zg);
        h8 sa0, sa1;
        if (l <= 3) { sa0 = s0a[l]; sa1 = s1a[l]; }
        else if (l == 4) {
          if (t < 16) {
            #pragma unroll
            for (int u = 0; u < 4; ++u) {
              sa0[u] = (_Float16)p4[0][u]; sa0[u + 4] = (_Float16)p4[1][u];
              sa1[u] = (_Float16)p4[2][u]; sa1[u + 4] = (_Float16)p4[3][u];
            }
          } else { sa0 = s4a0; sa1 = s4a1; }
        } else {
          #pragma unroll
          for (int u = 0; u < 4; ++u) {
            sa0[u] = (_Float16)p5[0][u]; sa0[u + 4] = (_Float16)p5[1][u];
            sa1[u] = (_Float16)p5[2][u]; sa1[u + 4] = (_Float16)p5[3][u];
          }
        }
        f4v dcf = Zf, dcg = Zg;
        dcf = MFMA16(sa0, BW2f[0], dcf); dcf = MFMA16(sa1, BW2f[1], dcf);
        dcg = MFMA16(sa0, BW2g[0], dcg); dcg = MFMA16(sa1, BW2g[1], dcg);
        #pragma unroll
        for (int r = 0; r < 4; ++r) {
          const float gd = tanh_fast(dcf[r] + b2f) * sig_fast(dcg[r] + b2g);
          g16v[l & 1][4 * q + r][cf] = (_Float16)gd;
        }
      } else {
        const int lp  = l - 1;
        const int dlp = 1 << lp;
        const int slotlp = (lp <= 3) ? (dlp - 1) + (t & (dlp - 1)) : 15 + (t & 7);
        f4v osk = {0,0,0,0}, ore = {0,0,0,0};
        osk = MFMA16(gA0, B4s[0], osk); osk = MFMA16(gA1, B4s[1], osk);
        ore = MFMA16(gA0, B4r[0], ore); ore = MFMA16(gA1, B4r[1], ore);
        const bool wr = (t + dlp) <= 23;
        #pragma unroll
        for (int r = 0; r < 4; ++r) {
          skbuf[((size_t)(e0 + 4 * q + r) * TPRED + t) * 384 + lp * 64 + cs] =
              (_Float16)fmaxf(osk[r] + b4s_b, 0.0f);
          const float xn = xreg[r] + ore[r] + b4r_b;
          xreg[r] = xn;
          if (wr) ring[slotlp][4 * q + r][cs] = (_Float16)xn;
        }
      }
      LBAR();
    }

    // ======== T: lagged skip for l=5; embed for t+1 ========
    if (w >= 4) {
      const h8 gA0 = *(const h8*)&g16v[1][i][q8];
      const h8 gA1 = *(const h8*)&g16v[1][i][32 + q8];
      f4v osk = {0,0,0,0};
      osk = MFMA16(gA0, B4s[0], osk); osk = MFMA16(gA1, B4s[1], osk);
      #pragma unroll
      for (int r = 0; r < 4; ++r)
        skbuf[((size_t)(e0 + 4 * q + r) * TPRED + t) * 384 + 5 * 64 + cs] =
            (_Float16)fmaxf(osk[r] + b4s_b, 0.0f);
    }
    if (t + 1 < t_steps) {
      #pragma unroll
      for (int s = 0; s < 2; ++s) {
        const int el = 2 * w + s;
        float u = b1r + (s ? ini1 : ini0) * w1r[0];
        u += pfa[s][0] * w1r[1]  + pfa[s][1] * w1r[2]  + pfa[s][2] * w1r[3]  + pfa[s][3] * w1r[4];
        u += pfb[s][0] * w1r[5]  + pfb[s][1] * w1r[6]  + pfb[s][2] * w1r[7]  + pfb[s][3] * w1r[8];
        u += pfc[s][0] * w1r[9]  + pfc[s][1] * w1r[10] + pfc[s][2] * w1r[11] + pfc[s][3] * w1r[12];
        u += pfd[s].x  * w1r[13] + pfd[s].y  * w1r[14] + pfe[s]    * w1r[15];
        const float xv = tanh_fast(u);
        xf16[el][ln] = (_Float16)xv;
        xf32[ln][el] = xv;
      }
    }
    LBAR();
  }
}

// ---------------------------------------------------------------------------
// Phase 2: y = relu( sk @ W5 + b5 ) @ W6 + b6, 49152 rows, f16 MFMA.
// 256 blocks x 192 rows (exact, no tail). A staged to LDS in two row-halves
// (loads for both issued up front; compute of half 1 overlaps write of half 2).
// ---------------------------------------------------------------------------
__global__ __launch_bounds__(512, 1) void dec_phase2(
    const _Float16* __restrict__ skbuf,  // [49152][384] f16 (already relu'd)
    const float* __restrict__ W5,        // [384][128]
    const float* __restrict__ b5,        // [128]
    const float* __restrict__ W6,        // [128]
    const float* __restrict__ b6,        // [1]
    float* __restrict__ out)             // [49152]
{
  __shared__ _Float16 As[192][392];      // 147.0 KB
  __shared__ float red[192][8];          // 6.0 KB

  const int tid = threadIdx.x;
  const int w   = tid >> 6;
  const int ln  = tid & 63;
  const int i   = ln & 15;
  const int q   = ln >> 4;
  const int R0  = blockIdx.x * 192;
  const int col = 16 * w + i;

  h8 B5[12];
  #pragma unroll
  for (int kk = 0; kk < 12; ++kk)
    #pragma unroll
    for (int j = 0; j < 8; ++j)
      B5[kk][j] = (_Float16)W5[(size_t)(kk * 32 + q * 8 + j) * 128 + col];
  const float b5r = b5[col], w6r = W6[col];

  // issue all global loads (rows 0..95 -> v1, rows 96..191 -> v2)
  h8 v1[9], v2[9];
  #pragma unroll
  for (int it = 0; it < 9; ++it) {
    const int idx = tid + it * 512;
    v1[it] = *(const h8*)&skbuf[(size_t)(R0 + idx / 48) * 384 + (idx % 48) * 8];
  }
  #pragma unroll
  for (int it = 0; it < 9; ++it) {
    const int idx = 4608 + tid + it * 512;
    v2[it] = *(const h8*)&skbuf[(size_t)(R0 + idx / 48) * 384 + (idx % 48) * 8];
  }
  #pragma unroll
  for (int it = 0; it < 9; ++it) {
    const int idx = tid + it * 512;
    *(h8*)&As[idx / 48][(idx % 48) * 8] = v1[it];
  }
  __syncthreads();
  #pragma unroll
  for (int it = 0; it < 9; ++it) {
    const int idx = 4608 + tid + it * 512;
    *(h8*)&As[idx / 48][(idx % 48) * 8] = v2[it];
  }

  // compute m=0..5 (rows 0..95) while half-2 writes land
  #pragma unroll
  for (int m = 0; m < 12; ++m) {
    if (m == 6) __syncthreads();
    f4v acc = {0,0,0,0};
    #pragma unroll
    for (int kk = 0; kk < 12; ++kk) {
      const h8 a = *(const h8*)&As[16 * m + i][kk * 32 + q * 8];
      acc = MFMA16(a, B5[kk], acc);
    }
    float py[4];
    #pragma unroll
    for (int r = 0; r < 4; ++r)
      py[r] = fmaxf(acc[r] + b5r, 0.0f) * w6r;
    #pragma unroll
    for (int r = 0; r < 4; ++r) {
      float v = py[r];
      v += __shfl_xor(v, 1);
      v += __shfl_xor(v, 2);
      v += __shfl_xor(v, 4);
      v += __shfl_xor(v, 8);
      py[r] = v;
    }
    if (i == 0) {
      #pragma unroll
      for (int r = 0; r < 4; ++r) red[16 * m + 4 * q + r][w] = py[r];
    }
  }
  __syncthreads();

  if (tid < 192) {
    const f4v r0 = *(const f4v*)&red[tid][0];
    const f4v r1 = *(const f4v*)&red[tid][4];
    out[R0 + tid] = b6[0] + r0[0] + r0[1] + r0[2] + r0[3]
                          + r1[0] + r1[1] + r1[2] + r1[3];
  }
}

extern "C" void kernel_launch(void* const* d_in, const int* in_sizes, int n_in,
                              void* d_out, int out_size, void* d_ws, size_t ws_size,
                              hipStream_t stream) {
  const float* feat  = (const float*)d_in[0];
  const float* dinit = (const float*)d_in[1];
  const float* enc   = (const float*)d_in[2];
  const float* W1    = (const float*)d_in[3];
  const float* b1    = (const float*)d_in[4];
  const float* W2    = (const float*)d_in[5];
  const float* b2    = (const float*)d_in[6];
  const float* W3    = (const float*)d_in[7];
  const float* W4    = (const float*)d_in[8];
  const float* b4    = (const float*)d_in[9];
  const float* W5    = (const float*)d_in[10];
  const float* b5    = (const float*)d_in[11];
  const float* W6    = (const float*)d_in[12];
  const float* b6    = (const float*)d_in[13];

  float*     out   = (float*)d_out;
  _Float16*  skbuf = (_Float16*)d_ws;   // 49152*384*2 = 37.7 MB workspace

  dec_phase1<<<dim3(128), dim3(512), 0, stream>>>(
      feat, dinit, enc, W1, b1, W2, b2, W3, W4, b4, skbuf, TPRED);
  dec_phase2<<<dim3(256), dim3(512), 0, stream>>>(
      skbuf, W5, b5, W6, b6, out);
}